// Round 11
// baseline (436.005 us; speedup 1.0000x reference)
//
#include <hip/hip_runtime.h>

// GraphSAGE x3 + BN(train stats) + ReLU + head. bf16 features/weights,
// fp32 MFMA accumulation, fp32 BN stats.
// R18: R17 (best=368.8us) + ONE change: 4-deep gather unroll in k_layer.
// R9's 4-unroll regression was VGPR->occupancy loss; here occupancy is
// thread-capped (4x512=2048) and launch_bounds(512,8) pins VGPR<=64, so
// deeper MLP is occupancy-free. Gather phase currently has only 2
// outstanding 16B gathers/lane-group at ~900cy HBM latency.

#define N_NODES 100000
#define N_EDGES 1250000
#define NB 1563         // buckets == row tiles (64 dst nodes each)
#define BSZ 64
#define CAP 1024        // slots per bucket (mean 800, sigma ~28)
#define BPART 256       // partition chunks (hist/scatter blocks)
#define INVN (1.0f / 100000.0f)

typedef short bf16x8 __attribute__((ext_vector_type(8)));
typedef float f32x4 __attribute__((ext_vector_type(4)));
typedef unsigned short u16x8 __attribute__((ext_vector_type(8)));
typedef unsigned short u16x4 __attribute__((ext_vector_type(4)));

__device__ __forceinline__ float bf2f(unsigned short u) {
  union { unsigned int i; float f; } c; c.i = ((unsigned int)u) << 16; return c.f;
}
__device__ __forceinline__ unsigned short f2bf(float f) {
  union { float f; unsigned int i; } c; c.f = f;
  unsigned int r = (c.i + 0x7FFFu + ((c.i >> 16) & 1u)) >> 16;  // RNE
  return (unsigned short)r;
}
// stats layout per layer: [4 replicas][2][128] = 1024 floats
__device__ __forceinline__ void bn_st(const float* stats, const float* gam,
                                      const float* bet, int c, float& s, float& t) {
  float sum = stats[c] + stats[256 + c] + stats[512 + c] + stats[768 + c];
  float sq  = stats[128 + c] + stats[384 + c] + stats[640 + c] + stats[896 + c];
  float mu = sum * INVN;
  float var = sq * INVN - mu * mu;
  s = gam[c] * rsqrtf(var + 1e-5f);
  t = bet[c] - mu * s;
}
// async global->LDS, 16B per lane; lds base must be wave-uniform.
__device__ __forceinline__ void gload_lds16(const void* g, void* l) {
  __builtin_amdgcn_global_load_lds(
      (const __attribute__((address_space(1))) unsigned int*)g,
      (__attribute__((address_space(3))) unsigned int*)l, 16, 0, 0);
}

// ----------------- prep: f2bf(x) + weight transpose + init + hist ---------
__global__ __launch_bounds__(256) void k_prep(
    const float* __restrict__ x, unsigned short* __restrict__ x16,
    const float* __restrict__ W0s, const float* __restrict__ W0n,
    const float* __restrict__ W1s, const float* __restrict__ W1n,
    const float* __restrict__ W2s, const float* __restrict__ W2n,
    unsigned short* __restrict__ wt, float* __restrict__ stats3,
    const int* __restrict__ dst, int* __restrict__ hist, int E) {
  __shared__ int hh[NB];
  int blk = blockIdx.x, t = threadIdx.x;
  if (blk < 6250) {
    int i = blk * 256 + t;
    float4 v = ((const float4*)x)[i];
    u16x4 o;
    o.x = f2bf(v.x); o.y = f2bf(v.y); o.z = f2bf(v.z); o.w = f2bf(v.w);
    ((u16x4*)x16)[i] = o;
  } else if (blk < 6570) {
    int i = (blk - 6250) * 256 + t;
    if (i < 16384) {
      const float* W = (i < 8192) ? W0s : W0n;
      unsigned short* o = wt + (i < 8192 ? 0 : 8192);
      int j = i & 8191;
      int c = j >> 6, k = j & 63;
      o[j] = f2bf(W[k * 128 + c]);
    } else {
      int j = i - 16384;
      int sel = j >> 14;
      j &= 16383;
      const float* W = (sel == 0) ? W1s : (sel == 1) ? W1n : (sel == 2) ? W2s : W2n;
      unsigned short* o = wt + 16384 + sel * 16384;
      int c = j >> 7, k = j & 127;
      o[j] = f2bf(W[k * 128 + c]);
    }
  } else if (blk == 6570) {
    for (int i = t; i < 3 * 1024; i += 256) stats3[i] = 0.f;
  } else {
    // per-chunk histogram (merged k_hist)
    int hb = blk - 6571;
    int chunk = (E + BPART - 1) / BPART;
    int start = hb * chunk;
    int end = min(E, start + chunk);
    for (int b = t; b < NB; b += 256) hh[b] = 0;
    __syncthreads();
    for (int e = start + t; e < end; e += 256) atomicAdd(&hh[dst[e] >> 6], 1);
    __syncthreads();
    for (int b = t; b < NB; b += 256) hist[hb * NB + b] = hh[b];
  }
}

// ----------------- partition pass 2: per-bucket scan over chunks -----------
__global__ __launch_bounds__(256) void k_scan(const int* __restrict__ hist,
                                              int* __restrict__ base,
                                              int* __restrict__ gcursor) {
  int bb = blockIdx.x * 256 + threadIdx.x;
  if (bb >= NB) return;
  int run = 0;
  for (int r0 = 0; r0 < BPART; r0 += 16) {
    int v[16];
    #pragma unroll
    for (int u = 0; u < 16; u++) v[u] = hist[(r0 + u) * NB + bb];
    #pragma unroll
    for (int u = 0; u < 16; u++) { base[(r0 + u) * NB + bb] = run; run += v[u]; }
  }
  gcursor[bb] = run;
}

// ----------------- partition pass 3: scatter with LDS cursors --------------
__global__ __launch_bounds__(256) void k_scatter(const int* __restrict__ src,
                                                 const int* __restrict__ dst,
                                                 const int* __restrict__ base,
                                                 unsigned int* __restrict__ part, int E) {
  __shared__ int cur[NB];
  int t = threadIdx.x;
  int chunk = (E + BPART - 1) / BPART;
  int start = blockIdx.x * chunk;
  int end = min(E, start + chunk);
  for (int b = t; b < NB; b += 256) cur[b] = base[blockIdx.x * NB + b];
  __syncthreads();
  for (int e = start + t; e < end; e += 256) {
    int d = dst[e];
    int b = d >> 6;
    int pos = atomicAdd(&cur[b], 1);
    if ((unsigned)pos < (unsigned)CAP)
      part[(size_t)b * CAP + pos] = (unsigned)src[e] | ((unsigned)(d & 63) << 17);
  }
}

// ----------------- fused layer: CSR + gather(+BN) + 64x128 MFMA GEMM ------
// C[bucket rows] = bnrelu?(h[rows])@W1 + mean(bnrelu?(h[src]))@W2 + bias,
// + stats partials. neighT lives in LDS (XOR-swizzled); self A-frags read
// from global (L2-warm after gather). Bs double-buffered (one barrier/step).
template <int DIN, bool BN>
__global__ __launch_bounds__(512, 8) void k_layer(
    const unsigned short* __restrict__ h, const unsigned short* __restrict__ W1t,
    const unsigned short* __restrict__ W2t, const float* __restrict__ bias,
    const unsigned int* __restrict__ part, const int* __restrict__ gcursor,
    unsigned short* __restrict__ C, float* __restrict__ stats, int M,
    const float* __restrict__ statsP, const float* __restrict__ gamP,
    const float* __restrict__ betP) {
  __shared__ unsigned short neighT[64 * DIN];  // 16KB(128)/8KB(64); eraw overlay
  __shared__ unsigned eord[CAP];               // 4KB; redS/redQ overlay
  __shared__ unsigned short Bs[2][128 * 32];   // 16KB W k-chunk (dbuf)
  __shared__ int cnt[BSZ], offv[BSZ], cur[BSZ];
  __shared__ int stealCtr;
  __shared__ float sBN[128], tBN[128];
  unsigned* eraw = (unsigned*)neighT;          // dead before gather writes
  float* redS = (float*)eord;                  // [8][64]; eord dead at epilogue
  float* redQ = redS + 512;

  constexpr int SWZM = (DIN == 128) ? 15 : 7;  // neighT chunk-swizzle mask
  constexpr int KS = DIN / 32;                 // k-steps per half
  int t = threadIdx.x;
  int lane = t & 63, w = t >> 6;
  int l15 = lane & 15, quad = lane >> 4;
  int bkt = blockIdx.x;
  int node0 = bkt * BSZ;
  int nn = min(BSZ, M - node0);

  // ---- init ----
  if (t < BSZ) cnt[t] = 0;
  if (t == 0) stealCtr = 0;
  if (BN && t < 128) bn_st(statsP, gamP, betP, t, sBN[t], tBN[t]);
  __syncthreads();

  // ---- CSR build (bucket-local counting sort) ----
  int ec = gcursor[bkt];
  ec = max(0, min(ec, CAP));
  for (int i = t; i < ec; i += 512) {
    unsigned wd = part[(size_t)bkt * CAP + i];
    eraw[i] = wd;
    atomicAdd(&cnt[wd >> 17], 1);
  }
  __syncthreads();
  // wave-0 shfl exclusive scan over the 64 bucket counts (BSZ == wave size)
  if (w == 0) {
    int v = cnt[lane];
    int incl = v;
    #pragma unroll
    for (int o = 1; o < 64; o <<= 1) {
      int u = __shfl_up(incl, o);
      if (lane >= o) incl += u;
    }
    offv[lane] = incl - v;
    cur[lane] = incl - v;
  }
  __syncthreads();
  for (int i = t; i < ec; i += 512) {
    unsigned wd = eraw[i];
    int p = atomicAdd(&cur[wd >> 17], 1);
    eord[p] = wd & 0x1FFFF;
  }
  __syncthreads();  // eraw (neighT space) dead

  // ---- gather + mean (+BN per edge) — 4-deep MLP (R18) ----
  const int G = DIN / 8;
  int li = t & (G - 1);
  float sreg[8], treg[8];
  if (BN) {
    #pragma unroll
    for (int k = 0; k < 8; k++) { sreg[k] = sBN[li * 8 + k]; treg[k] = tBN[li * 8 + k]; }
  }
  for (;;) {
    int nd0 = 0;
    if (li == 0) nd0 = atomicAdd(&stealCtr, 1);
    int nd = __shfl(nd0, 0, G);
    if (nd >= BSZ) break;
    u16x8 o;
    if (nd >= nn) {
      #pragma unroll
      for (int k = 0; k < 8; k++) o[k] = 0;
    } else {
      int s = offv[nd], c = cnt[nd];
      int e = s + c;
      float acc[8] = {0.f, 0.f, 0.f, 0.f, 0.f, 0.f, 0.f, 0.f};
      int j = s;
      for (; j + 4 <= e; j += 4) {  // 4 outstanding 16B gathers per lane
        int a0 = eord[j], a1 = eord[j + 1], a2 = eord[j + 2], a3 = eord[j + 3];
        u16x8 v0 = *(const u16x8*)&h[(size_t)a0 * DIN + li * 8];
        u16x8 v1 = *(const u16x8*)&h[(size_t)a1 * DIN + li * 8];
        u16x8 v2 = *(const u16x8*)&h[(size_t)a2 * DIN + li * 8];
        u16x8 v3 = *(const u16x8*)&h[(size_t)a3 * DIN + li * 8];
        if (BN) {
          #pragma unroll
          for (int k = 0; k < 8; k++)
            acc[k] += fmaxf(fmaf(bf2f(v0[k]), sreg[k], treg[k]), 0.f)
                    + fmaxf(fmaf(bf2f(v1[k]), sreg[k], treg[k]), 0.f)
                    + fmaxf(fmaf(bf2f(v2[k]), sreg[k], treg[k]), 0.f)
                    + fmaxf(fmaf(bf2f(v3[k]), sreg[k], treg[k]), 0.f);
        } else {
          #pragma unroll
          for (int k = 0; k < 8; k++)
            acc[k] += (bf2f(v0[k]) + bf2f(v1[k])) + (bf2f(v2[k]) + bf2f(v3[k]));
        }
      }
      for (; j + 2 <= e; j += 2) {
        int a0 = eord[j], a1 = eord[j + 1];
        u16x8 v0 = *(const u16x8*)&h[(size_t)a0 * DIN + li * 8];
        u16x8 v1 = *(const u16x8*)&h[(size_t)a1 * DIN + li * 8];
        if (BN) {
          #pragma unroll
          for (int k = 0; k < 8; k++)
            acc[k] += fmaxf(fmaf(bf2f(v0[k]), sreg[k], treg[k]), 0.f)
                    + fmaxf(fmaf(bf2f(v1[k]), sreg[k], treg[k]), 0.f);
        } else {
          #pragma unroll
          for (int k = 0; k < 8; k++) acc[k] += bf2f(v0[k]) + bf2f(v1[k]);
        }
      }
      if (j < e) {
        int sn = eord[j];
        u16x8 v = *(const u16x8*)&h[(size_t)sn * DIN + li * 8];
        if (BN) {
          #pragma unroll
          for (int k = 0; k < 8; k++)
            acc[k] += fmaxf(fmaf(bf2f(v[k]), sreg[k], treg[k]), 0.f);
        } else {
          #pragma unroll
          for (int k = 0; k < 8; k++) acc[k] += bf2f(v[k]);
        }
      }
      float inv = 1.0f / fmaxf((float)c, 1.0f);
      #pragma unroll
      for (int k = 0; k < 8; k++) o[k] = f2bf(acc[k] * inv);
    }
    *(u16x8*)&neighT[nd * DIN + ((li * 8) ^ ((nd & SWZM) << 3))] = o;
  }

  // ---- GEMM: 64 rows x 128 cols; Bs dbuf, one barrier per k-step ----
  const int strip = w >> 1;
  const int ch = w & 1;
  const int row = strip * 16 + l15;
  f32x4 acc4[4];
  #pragma unroll
  for (int ct = 0; ct < 4; ct++) acc4[ct] = (f32x4){0.f, 0.f, 0.f, 0.f};

  auto stageBs = [&](int s, int bi) {  // coalesced, linear LDS
    const unsigned short* Wt = (s < KS) ? W1t : W2t;
    int k0 = ((s < KS) ? s : s - KS) * 32;
    int r = t >> 2, prt = t & 3;
    gload_lds16(&Wt[(size_t)r * DIN + k0 + prt * 8], &Bs[bi][(w * 64) * 8]);
  };
  stageBs(0, 0);
  __syncthreads();  // neighT published + Bs(0) drained

  int cb = 0;
  #pragma unroll
  for (int s = 0; s < 2 * KS; s++) {
    if (s + 1 < 2 * KS) stageBs(s + 1, cb ^ 1);
    bf16x8 af;
    if (s < KS) {  // self half: A from global h (L2-warm), optional BN
      int k0 = s * 32;
      u16x8 v = *(const u16x8*)&h[(size_t)(node0 + row) * DIN + k0 + quad * 8];
      if (BN) {
        #pragma unroll
        for (int j = 0; j < 8; j++) {
          int c = k0 + quad * 8 + j;
          v[j] = f2bf(fmaxf(fmaf(bf2f(v[j]), sBN[c], tBN[c]), 0.f));
        }
      }
      af = *(bf16x8*)&v;
    } else {  // neigh half: A from swizzled neighT
      int cc = (s - KS) * 32 + quad * 8;
      u16x8 v = *(const u16x8*)&neighT[row * DIN + (cc ^ ((row & SWZM) << 3))];
      af = *(bf16x8*)&v;
    }
    #pragma unroll
    for (int ct = 0; ct < 4; ct++) {
      bf16x8 bfr = *(const bf16x8*)&Bs[cb][(ch * 64 + ct * 16 + l15) * 32 + quad * 8];
      acc4[ct] = __builtin_amdgcn_mfma_f32_16x16x32_bf16(af, bfr, acc4[ct], 0, 0, 0);
    }
    if (s + 1 < 2 * KS) __syncthreads();  // Bs(s+1) landed; Bs(cb) consumed
    cb ^= 1;
  }

  // ---- epilogue: bias, C write, stats partials ----
  float bcol[4], ls[4], lq[4];
  #pragma unroll
  for (int ct = 0; ct < 4; ct++) {
    bcol[ct] = bias[ch * 64 + ct * 16 + l15];
    ls[ct] = 0.f; lq[ct] = 0.f;
  }
  #pragma unroll
  for (int r = 0; r < 4; r++) {
    int orow = node0 + strip * 16 + quad * 4 + r;
    if (orow < M) {
      #pragma unroll
      for (int ct = 0; ct < 4; ct++) {
        float v = acc4[ct][r] + bcol[ct];
        C[(size_t)orow * 128 + ch * 64 + ct * 16 + l15] = f2bf(v);
        ls[ct] += v; lq[ct] += v * v;
      }
    }
  }
  #pragma unroll
  for (int ct = 0; ct < 4; ct++) {  // reduce over quads (rows of strip)
    ls[ct] += __shfl_xor(ls[ct], 16); ls[ct] += __shfl_xor(ls[ct], 32);
    lq[ct] += __shfl_xor(lq[ct], 16); lq[ct] += __shfl_xor(lq[ct], 32);
  }
  if (quad == 0) {
    #pragma unroll
    for (int ct = 0; ct < 4; ct++) {
      redS[w * 64 + ct * 16 + l15] = ls[ct];
      redQ[w * 64 + ct * 16 + l15] = lq[ct];
    }
  }
  __syncthreads();
  if (t < 128) {
    int ch2 = t >> 6, c6 = t & 63;
    float s = 0.f, q = 0.f;
    #pragma unroll
    for (int st = 0; st < 4; st++) {
      s += redS[(st * 2 + ch2) * 64 + c6];
      q += redQ[(st * 2 + ch2) * 64 + c6];
    }
    int rep = (bkt & 3) * 256;  // 4 replicas
    atomicAdd(&stats[rep + t], s);
    atomicAdd(&stats[rep + 128 + t], q);
  }
}

// ----------------- fused BN + ReLU + classifier -----------------
__global__ void k_final(const unsigned short* __restrict__ h,
                        const float* __restrict__ statsP, const float* __restrict__ gamP,
                        const float* __restrict__ betP, const float* __restrict__ Wc,
                        const float* __restrict__ bc, float* __restrict__ out, int n) {
  int lane = threadIdx.x & 63;
  int row = blockIdx.x * (blockDim.x >> 6) + (threadIdx.x >> 6);
  if (row >= n) return;
  float acc0 = 0.f, acc1 = 0.f;
  #pragma unroll
  for (int m = 0; m < 2; m++) {
    int c = lane + 64 * m;
    float s, tt;
    bn_st(statsP, gamP, betP, c, s, tt);
    float v = bf2f(h[(size_t)row * 128 + c]);
    v = fmaxf(fmaf(v, s, tt), 0.f);
    acc0 += v * Wc[c * 2 + 0];
    acc1 += v * Wc[c * 2 + 1];
  }
  #pragma unroll
  for (int off = 32; off > 0; off >>= 1) {
    acc0 += __shfl_down(acc0, off);
    acc1 += __shfl_down(acc1, off);
  }
  if (lane == 0) {
    out[row * 2 + 0] = acc0 + bc[0];
    out[row * 2 + 1] = acc1 + bc[1];
  }
}

extern "C" void kernel_launch(void* const* d_in, const int* in_sizes, int n_in,
                              void* d_out, int out_size, void* d_ws, size_t ws_size,
                              hipStream_t stream) {
  const float* x   = (const float*)d_in[0];
  const int* src   = (const int*)d_in[1];
  const int* dst   = (const int*)d_in[2];
  const float* Wself[3] = {(const float*)d_in[3], (const float*)d_in[8],  (const float*)d_in[13]};
  const float* bself[3] = {(const float*)d_in[4], (const float*)d_in[9],  (const float*)d_in[14]};
  const float* Wngh[3]  = {(const float*)d_in[5], (const float*)d_in[10], (const float*)d_in[15]};
  const float* gam[3]   = {(const float*)d_in[6], (const float*)d_in[11], (const float*)d_in[16]};
  const float* bet[3]   = {(const float*)d_in[7], (const float*)d_in[12], (const float*)d_in[17]};
  const float* Wc = (const float*)d_in[18];
  const float* bc = (const float*)d_in[19];
  float* out = (float*)d_out;

  const int N = N_NODES, E = N_EDGES;

  unsigned short* x16 = (unsigned short*)d_ws;        // N*64
  unsigned short* b0  = x16 + (size_t)N * 64;         // N*128 (slack)
  unsigned short* b1  = b0 + (size_t)N * 128;
  unsigned short* b2  = b1 + (size_t)N * 128;
  unsigned short* wt  = b2 + (size_t)N * 128;         // 81920
  unsigned int* part  = (unsigned int*)(wt + 81920);  // NB*CAP
  int* gcursor  = (int*)(part + (size_t)NB * CAP);    // NB
  float* stats3 = (float*)(gcursor + NB);             // 3*1024

  // hist/base (BPART*NB ints = 1.6MB each) alias into b1 — b1 is first
  // written by layer0's k_layer, stream-ordered after scan/scatter.
  int* hist = (int*)b1;
  int* base = hist + (size_t)BPART * NB;

  // ---- prep: x->bf16, weights, stats zero, edge hist ----
  k_prep<<<6571 + BPART, 256, 0, stream>>>(
      x, x16, Wself[0], Wngh[0], Wself[1], Wngh[1], Wself[2], Wngh[2],
      wt, stats3, dst, hist, E);

  // ---- partition: scan -> scatter ----
  k_scan<<<(NB + 255) / 256, 256, 0, stream>>>(hist, base, gcursor);
  k_scatter<<<BPART, 256, 0, stream>>>(src, dst, base, part, E);

  // ---- fused layers ----
  k_layer<64, false><<<NB, 512, 0, stream>>>(
      x16, wt + 0, wt + 8192, bself[0], part, gcursor, b1, stats3 + 0, N,
      nullptr, nullptr, nullptr);
  k_layer<128, true><<<NB, 512, 0, stream>>>(
      b1, wt + 16384, wt + 32768, bself[1], part, gcursor, b2, stats3 + 1024, N,
      stats3 + 0, gam[0], bet[0]);
  k_layer<128, true><<<NB, 512, 0, stream>>>(
      b2, wt + 49152, wt + 65536, bself[2], part, gcursor, b1, stats3 + 2048, N,
      stats3 + 1024, gam[1], bet[1]);

  // ---- fused BN2 + ReLU + classifier ----
  k_final<<<(N + 3) / 4, 256, 0, stream>>>(b1, stats3 + 2048, gam[2], bet[2],
                                           Wc, bc, out, N);
}

// Round 12
// 357.535 us; speedup vs baseline: 1.2195x; 1.2195x over previous
//
#include <hip/hip_runtime.h>

// GraphSAGE x3 + BN(train stats) + ReLU + head. bf16 features/weights,
// fp32 MFMA accumulation, fp32 BN stats.
// R19: revert to R17 (best=368.8; R18's 4-deep gather thrashed L2:
// WRITE 26.8->173MB). Two non-hot-path changes only:
//  - stats replicas 4->8 (halve k_layer epilogue same-address atomic
//    chains, ~390->~195 deep)
//  - k_final: LDS BN-coeff precompute + u16x2 h loads + float4 Wc loads
// k_layer gather/GEMM byte-identical to R17 (2-deep unroll).

#define N_NODES 100000
#define N_EDGES 1250000
#define NB 1563         // buckets == row tiles (64 dst nodes each)
#define BSZ 64
#define CAP 1024        // slots per bucket (mean 800, sigma ~28)
#define BPART 256       // partition chunks (hist/scatter blocks)
#define NREP 8          // stats replicas (per layer: [NREP][2][128])
#define INVN (1.0f / 100000.0f)

typedef short bf16x8 __attribute__((ext_vector_type(8)));
typedef float f32x4 __attribute__((ext_vector_type(4)));
typedef unsigned short u16x8 __attribute__((ext_vector_type(8)));
typedef unsigned short u16x4 __attribute__((ext_vector_type(4)));
typedef unsigned short u16x2 __attribute__((ext_vector_type(2)));

__device__ __forceinline__ float bf2f(unsigned short u) {
  union { unsigned int i; float f; } c; c.i = ((unsigned int)u) << 16; return c.f;
}
__device__ __forceinline__ unsigned short f2bf(float f) {
  union { float f; unsigned int i; } c; c.f = f;
  unsigned int r = (c.i + 0x7FFFu + ((c.i >> 16) & 1u)) >> 16;  // RNE
  return (unsigned short)r;
}
// stats layout per layer: [NREP replicas][2][128] floats
__device__ __forceinline__ void bn_st(const float* stats, const float* gam,
                                      const float* bet, int c, float& s, float& t) {
  float sum = 0.f, sq = 0.f;
  #pragma unroll
  for (int r = 0; r < NREP; r++) {
    sum += stats[r * 256 + c];
    sq  += stats[r * 256 + 128 + c];
  }
  float mu = sum * INVN;
  float var = sq * INVN - mu * mu;
  s = gam[c] * rsqrtf(var + 1e-5f);
  t = bet[c] - mu * s;
}
// async global->LDS, 16B per lane; lds base must be wave-uniform.
__device__ __forceinline__ void gload_lds16(const void* g, void* l) {
  __builtin_amdgcn_global_load_lds(
      (const __attribute__((address_space(1))) unsigned int*)g,
      (__attribute__((address_space(3))) unsigned int*)l, 16, 0, 0);
}

// ----------------- prep: f2bf(x) + weight transpose + init + hist ---------
__global__ __launch_bounds__(256) void k_prep(
    const float* __restrict__ x, unsigned short* __restrict__ x16,
    const float* __restrict__ W0s, const float* __restrict__ W0n,
    const float* __restrict__ W1s, const float* __restrict__ W1n,
    const float* __restrict__ W2s, const float* __restrict__ W2n,
    unsigned short* __restrict__ wt, float* __restrict__ stats3,
    const int* __restrict__ dst, int* __restrict__ hist, int E) {
  __shared__ int hh[NB];
  int blk = blockIdx.x, t = threadIdx.x;
  if (blk < 6250) {
    int i = blk * 256 + t;
    float4 v = ((const float4*)x)[i];
    u16x4 o;
    o.x = f2bf(v.x); o.y = f2bf(v.y); o.z = f2bf(v.z); o.w = f2bf(v.w);
    ((u16x4*)x16)[i] = o;
  } else if (blk < 6570) {
    int i = (blk - 6250) * 256 + t;
    if (i < 16384) {
      const float* W = (i < 8192) ? W0s : W0n;
      unsigned short* o = wt + (i < 8192 ? 0 : 8192);
      int j = i & 8191;
      int c = j >> 6, k = j & 63;
      o[j] = f2bf(W[k * 128 + c]);
    } else {
      int j = i - 16384;
      int sel = j >> 14;
      j &= 16383;
      const float* W = (sel == 0) ? W1s : (sel == 1) ? W1n : (sel == 2) ? W2s : W2n;
      unsigned short* o = wt + 16384 + sel * 16384;
      int c = j >> 7, k = j & 127;
      o[j] = f2bf(W[k * 128 + c]);
    }
  } else if (blk == 6570) {
    for (int i = t; i < 3 * NREP * 256; i += 256) stats3[i] = 0.f;
  } else {
    // per-chunk histogram (merged k_hist)
    int hb = blk - 6571;
    int chunk = (E + BPART - 1) / BPART;
    int start = hb * chunk;
    int end = min(E, start + chunk);
    for (int b = t; b < NB; b += 256) hh[b] = 0;
    __syncthreads();
    for (int e = start + t; e < end; e += 256) atomicAdd(&hh[dst[e] >> 6], 1);
    __syncthreads();
    for (int b = t; b < NB; b += 256) hist[hb * NB + b] = hh[b];
  }
}

// ----------------- partition pass 2: per-bucket scan over chunks -----------
__global__ __launch_bounds__(256) void k_scan(const int* __restrict__ hist,
                                              int* __restrict__ base,
                                              int* __restrict__ gcursor) {
  int bb = blockIdx.x * 256 + threadIdx.x;
  if (bb >= NB) return;
  int run = 0;
  for (int r0 = 0; r0 < BPART; r0 += 16) {
    int v[16];
    #pragma unroll
    for (int u = 0; u < 16; u++) v[u] = hist[(r0 + u) * NB + bb];
    #pragma unroll
    for (int u = 0; u < 16; u++) { base[(r0 + u) * NB + bb] = run; run += v[u]; }
  }
  gcursor[bb] = run;
}

// ----------------- partition pass 3: scatter with LDS cursors --------------
__global__ __launch_bounds__(256) void k_scatter(const int* __restrict__ src,
                                                 const int* __restrict__ dst,
                                                 const int* __restrict__ base,
                                                 unsigned int* __restrict__ part, int E) {
  __shared__ int cur[NB];
  int t = threadIdx.x;
  int chunk = (E + BPART - 1) / BPART;
  int start = blockIdx.x * chunk;
  int end = min(E, start + chunk);
  for (int b = t; b < NB; b += 256) cur[b] = base[blockIdx.x * NB + b];
  __syncthreads();
  for (int e = start + t; e < end; e += 256) {
    int d = dst[e];
    int b = d >> 6;
    int pos = atomicAdd(&cur[b], 1);
    if ((unsigned)pos < (unsigned)CAP)
      part[(size_t)b * CAP + pos] = (unsigned)src[e] | ((unsigned)(d & 63) << 17);
  }
}

// ----------------- fused layer: CSR + gather(+BN) + 64x128 MFMA GEMM ------
// C[bucket rows] = bnrelu?(h[rows])@W1 + mean(bnrelu?(h[src]))@W2 + bias,
// + stats partials. neighT lives in LDS (XOR-swizzled); self A-frags read
// from global (L2-warm after gather). Bs double-buffered (one barrier/step).
template <int DIN, bool BN>
__global__ __launch_bounds__(512, 8) void k_layer(
    const unsigned short* __restrict__ h, const unsigned short* __restrict__ W1t,
    const unsigned short* __restrict__ W2t, const float* __restrict__ bias,
    const unsigned int* __restrict__ part, const int* __restrict__ gcursor,
    unsigned short* __restrict__ C, float* __restrict__ stats, int M,
    const float* __restrict__ statsP, const float* __restrict__ gamP,
    const float* __restrict__ betP) {
  __shared__ unsigned short neighT[64 * DIN];  // 16KB(128)/8KB(64); eraw overlay
  __shared__ unsigned eord[CAP];               // 4KB; redS/redQ overlay
  __shared__ unsigned short Bs[2][128 * 32];   // 16KB W k-chunk (dbuf)
  __shared__ int cnt[BSZ], offv[BSZ], cur[BSZ];
  __shared__ int stealCtr;
  __shared__ float sBN[128], tBN[128];
  unsigned* eraw = (unsigned*)neighT;          // dead before gather writes
  float* redS = (float*)eord;                  // [8][64]; eord dead at epilogue
  float* redQ = redS + 512;

  constexpr int SWZM = (DIN == 128) ? 15 : 7;  // neighT chunk-swizzle mask
  constexpr int KS = DIN / 32;                 // k-steps per half
  int t = threadIdx.x;
  int lane = t & 63, w = t >> 6;
  int l15 = lane & 15, quad = lane >> 4;
  int bkt = blockIdx.x;
  int node0 = bkt * BSZ;
  int nn = min(BSZ, M - node0);

  // ---- init ----
  if (t < BSZ) cnt[t] = 0;
  if (t == 0) stealCtr = 0;
  if (BN && t < 128) bn_st(statsP, gamP, betP, t, sBN[t], tBN[t]);
  __syncthreads();

  // ---- CSR build (bucket-local counting sort) ----
  int ec = gcursor[bkt];
  ec = max(0, min(ec, CAP));
  for (int i = t; i < ec; i += 512) {
    unsigned wd = part[(size_t)bkt * CAP + i];
    eraw[i] = wd;
    atomicAdd(&cnt[wd >> 17], 1);
  }
  __syncthreads();
  // wave-0 shfl exclusive scan over the 64 bucket counts (BSZ == wave size)
  if (w == 0) {
    int v = cnt[lane];
    int incl = v;
    #pragma unroll
    for (int o = 1; o < 64; o <<= 1) {
      int u = __shfl_up(incl, o);
      if (lane >= o) incl += u;
    }
    offv[lane] = incl - v;
    cur[lane] = incl - v;
  }
  __syncthreads();
  for (int i = t; i < ec; i += 512) {
    unsigned wd = eraw[i];
    int p = atomicAdd(&cur[wd >> 17], 1);
    eord[p] = wd & 0x1FFFF;
  }
  __syncthreads();  // eraw (neighT space) dead

  // ---- gather + mean (+BN per edge: free under memory bound) ----
  const int G = DIN / 8;
  int li = t & (G - 1);
  float sreg[8], treg[8];
  if (BN) {
    #pragma unroll
    for (int k = 0; k < 8; k++) { sreg[k] = sBN[li * 8 + k]; treg[k] = tBN[li * 8 + k]; }
  }
  for (;;) {
    int nd0 = 0;
    if (li == 0) nd0 = atomicAdd(&stealCtr, 1);
    int nd = __shfl(nd0, 0, G);
    if (nd >= BSZ) break;
    u16x8 o;
    if (nd >= nn) {
      #pragma unroll
      for (int k = 0; k < 8; k++) o[k] = 0;
    } else {
      int s = offv[nd], c = cnt[nd];
      int e = s + c;
      float acc[8] = {0.f, 0.f, 0.f, 0.f, 0.f, 0.f, 0.f, 0.f};
      int j = s;
      for (; j + 2 <= e; j += 2) {
        int sn0 = eord[j], sn1 = eord[j + 1];
        u16x8 v0 = *(const u16x8*)&h[(size_t)sn0 * DIN + li * 8];
        u16x8 v1 = *(const u16x8*)&h[(size_t)sn1 * DIN + li * 8];
        if (BN) {
          #pragma unroll
          for (int k = 0; k < 8; k++)
            acc[k] += fmaxf(fmaf(bf2f(v0[k]), sreg[k], treg[k]), 0.f)
                    + fmaxf(fmaf(bf2f(v1[k]), sreg[k], treg[k]), 0.f);
        } else {
          #pragma unroll
          for (int k = 0; k < 8; k++) acc[k] += bf2f(v0[k]) + bf2f(v1[k]);
        }
      }
      if (j < e) {
        int sn = eord[j];
        u16x8 v = *(const u16x8*)&h[(size_t)sn * DIN + li * 8];
        if (BN) {
          #pragma unroll
          for (int k = 0; k < 8; k++)
            acc[k] += fmaxf(fmaf(bf2f(v[k]), sreg[k], treg[k]), 0.f);
        } else {
          #pragma unroll
          for (int k = 0; k < 8; k++) acc[k] += bf2f(v[k]);
        }
      }
      float inv = 1.0f / fmaxf((float)c, 1.0f);
      #pragma unroll
      for (int k = 0; k < 8; k++) o[k] = f2bf(acc[k] * inv);
    }
    *(u16x8*)&neighT[nd * DIN + ((li * 8) ^ ((nd & SWZM) << 3))] = o;
  }

  // ---- GEMM: 64 rows x 128 cols; Bs dbuf, one barrier per k-step ----
  const int strip = w >> 1;
  const int ch = w & 1;
  const int row = strip * 16 + l15;
  f32x4 acc4[4];
  #pragma unroll
  for (int ct = 0; ct < 4; ct++) acc4[ct] = (f32x4){0.f, 0.f, 0.f, 0.f};

  auto stageBs = [&](int s, int bi) {  // coalesced, linear LDS
    const unsigned short* Wt = (s < KS) ? W1t : W2t;
    int k0 = ((s < KS) ? s : s - KS) * 32;
    int r = t >> 2, prt = t & 3;
    gload_lds16(&Wt[(size_t)r * DIN + k0 + prt * 8], &Bs[bi][(w * 64) * 8]);
  };
  stageBs(0, 0);
  __syncthreads();  // neighT published + Bs(0) drained

  int cb = 0;
  #pragma unroll
  for (int s = 0; s < 2 * KS; s++) {
    if (s + 1 < 2 * KS) stageBs(s + 1, cb ^ 1);
    bf16x8 af;
    if (s < KS) {  // self half: A from global h (L2-warm), optional BN
      int k0 = s * 32;
      u16x8 v = *(const u16x8*)&h[(size_t)(node0 + row) * DIN + k0 + quad * 8];
      if (BN) {
        #pragma unroll
        for (int j = 0; j < 8; j++) {
          int c = k0 + quad * 8 + j;
          v[j] = f2bf(fmaxf(fmaf(bf2f(v[j]), sBN[c], tBN[c]), 0.f));
        }
      }
      af = *(bf16x8*)&v;
    } else {  // neigh half: A from swizzled neighT
      int cc = (s - KS) * 32 + quad * 8;
      u16x8 v = *(const u16x8*)&neighT[row * DIN + (cc ^ ((row & SWZM) << 3))];
      af = *(bf16x8*)&v;
    }
    #pragma unroll
    for (int ct = 0; ct < 4; ct++) {
      bf16x8 bfr = *(const bf16x8*)&Bs[cb][(ch * 64 + ct * 16 + l15) * 32 + quad * 8];
      acc4[ct] = __builtin_amdgcn_mfma_f32_16x16x32_bf16(af, bfr, acc4[ct], 0, 0, 0);
    }
    if (s + 1 < 2 * KS) __syncthreads();  // Bs(s+1) landed; Bs(cb) consumed
    cb ^= 1;
  }

  // ---- epilogue: bias, C write, stats partials ----
  float bcol[4], ls[4], lq[4];
  #pragma unroll
  for (int ct = 0; ct < 4; ct++) {
    bcol[ct] = bias[ch * 64 + ct * 16 + l15];
    ls[ct] = 0.f; lq[ct] = 0.f;
  }
  #pragma unroll
  for (int r = 0; r < 4; r++) {
    int orow = node0 + strip * 16 + quad * 4 + r;
    if (orow < M) {
      #pragma unroll
      for (int ct = 0; ct < 4; ct++) {
        float v = acc4[ct][r] + bcol[ct];
        C[(size_t)orow * 128 + ch * 64 + ct * 16 + l15] = f2bf(v);
        ls[ct] += v; lq[ct] += v * v;
      }
    }
  }
  #pragma unroll
  for (int ct = 0; ct < 4; ct++) {  // reduce over quads (rows of strip)
    ls[ct] += __shfl_xor(ls[ct], 16); ls[ct] += __shfl_xor(ls[ct], 32);
    lq[ct] += __shfl_xor(lq[ct], 16); lq[ct] += __shfl_xor(lq[ct], 32);
  }
  if (quad == 0) {
    #pragma unroll
    for (int ct = 0; ct < 4; ct++) {
      redS[w * 64 + ct * 16 + l15] = ls[ct];
      redQ[w * 64 + ct * 16 + l15] = lq[ct];
    }
  }
  __syncthreads();
  if (t < 128) {
    int ch2 = t >> 6, c6 = t & 63;
    float s = 0.f, q = 0.f;
    #pragma unroll
    for (int st = 0; st < 4; st++) {
      s += redS[(st * 2 + ch2) * 64 + c6];
      q += redQ[(st * 2 + ch2) * 64 + c6];
    }
    int rep = (bkt & (NREP - 1)) * 256;  // NREP replicas (~195-deep chains)
    atomicAdd(&stats[rep + t], s);
    atomicAdd(&stats[rep + 128 + t], q);
  }
}

// ----------------- fused BN + ReLU + classifier -----------------
// R19: BN coeffs precomputed in LDS once per block; u16x2 h loads;
// float4 Wc loads (Wc row-major [128][2] -> lane covers channels 2l,2l+1).
__global__ __launch_bounds__(256) void k_final(
    const unsigned short* __restrict__ h,
    const float* __restrict__ statsP, const float* __restrict__ gamP,
    const float* __restrict__ betP, const float* __restrict__ Wc,
    const float* __restrict__ bc, float* __restrict__ out, int n) {
  __shared__ float sS[128], sT[128];
  int t = threadIdx.x;
  if (t < 128) bn_st(statsP, gamP, betP, t, sS[t], sT[t]);
  __syncthreads();
  int lane = t & 63;
  int row = blockIdx.x * 4 + (t >> 6);
  if (row >= n) return;
  int c0 = lane * 2;
  u16x2 hv = *(const u16x2*)&h[(size_t)row * 128 + c0];
  float4 w4 = ((const float4*)Wc)[lane];  // {Wc[c0][0],Wc[c0][1],Wc[c0+1][0],Wc[c0+1][1]}
  float v0 = fmaxf(fmaf(bf2f(hv.x), sS[c0], sT[c0]), 0.f);
  float v1 = fmaxf(fmaf(bf2f(hv.y), sS[c0 + 1], sT[c0 + 1]), 0.f);
  float acc0 = v0 * w4.x + v1 * w4.z;
  float acc1 = v0 * w4.y + v1 * w4.w;
  #pragma unroll
  for (int off = 32; off > 0; off >>= 1) {
    acc0 += __shfl_down(acc0, off);
    acc1 += __shfl_down(acc1, off);
  }
  if (lane == 0) {
    out[row * 2 + 0] = acc0 + bc[0];
    out[row * 2 + 1] = acc1 + bc[1];
  }
}

extern "C" void kernel_launch(void* const* d_in, const int* in_sizes, int n_in,
                              void* d_out, int out_size, void* d_ws, size_t ws_size,
                              hipStream_t stream) {
  const float* x   = (const float*)d_in[0];
  const int* src   = (const int*)d_in[1];
  const int* dst   = (const int*)d_in[2];
  const float* Wself[3] = {(const float*)d_in[3], (const float*)d_in[8],  (const float*)d_in[13]};
  const float* bself[3] = {(const float*)d_in[4], (const float*)d_in[9],  (const float*)d_in[14]};
  const float* Wngh[3]  = {(const float*)d_in[5], (const float*)d_in[10], (const float*)d_in[15]};
  const float* gam[3]   = {(const float*)d_in[6], (const float*)d_in[11], (const float*)d_in[16]};
  const float* bet[3]   = {(const float*)d_in[7], (const float*)d_in[12], (const float*)d_in[17]};
  const float* Wc = (const float*)d_in[18];
  const float* bc = (const float*)d_in[19];
  float* out = (float*)d_out;

  const int N = N_NODES, E = N_EDGES;

  unsigned short* x16 = (unsigned short*)d_ws;        // N*64
  unsigned short* b0  = x16 + (size_t)N * 64;         // N*128 (slack)
  unsigned short* b1  = b0 + (size_t)N * 128;
  unsigned short* b2  = b1 + (size_t)N * 128;
  unsigned short* wt  = b2 + (size_t)N * 128;         // 81920
  unsigned int* part  = (unsigned int*)(wt + 81920);  // NB*CAP
  int* gcursor  = (int*)(part + (size_t)NB * CAP);    // NB
  float* stats3 = (float*)(gcursor + NB);             // 3*NREP*256

  // hist/base (BPART*NB ints = 1.6MB each) alias into b1 — b1 is first
  // written by layer0's k_layer, stream-ordered after scan/scatter.
  int* hist = (int*)b1;
  int* base = hist + (size_t)BPART * NB;

  // ---- prep: x->bf16, weights, stats zero, edge hist ----
  k_prep<<<6571 + BPART, 256, 0, stream>>>(
      x, x16, Wself[0], Wngh[0], Wself[1], Wngh[1], Wself[2], Wngh[2],
      wt, stats3, dst, hist, E);

  // ---- partition: scan -> scatter ----
  k_scan<<<(NB + 255) / 256, 256, 0, stream>>>(hist, base, gcursor);
  k_scatter<<<BPART, 256, 0, stream>>>(src, dst, base, part, E);

  // ---- fused layers ----
  k_layer<64, false><<<NB, 512, 0, stream>>>(
      x16, wt + 0, wt + 8192, bself[0], part, gcursor, b1, stats3 + 0, N,
      nullptr, nullptr, nullptr);
  k_layer<128, true><<<NB, 512, 0, stream>>>(
      b1, wt + 16384, wt + 32768, bself[1], part, gcursor, b2, stats3 + 2048, N,
      stats3 + 0, gam[0], bet[0]);
  k_layer<128, true><<<NB, 512, 0, stream>>>(
      b2, wt + 49152, wt + 65536, bself[2], part, gcursor, b1, stats3 + 4096, N,
      stats3 + 2048, gam[1], bet[1]);

  // ---- fused BN2 + ReLU + classifier ----
  k_final<<<(N + 3) / 4, 256, 0, stream>>>(b1, stats3 + 4096, gam[2], bet[2],
                                           Wc, bc, out, N);
}

// Round 13
// 333.195 us; speedup vs baseline: 1.3086x; 1.0730x over previous
//
#include <hip/hip_runtime.h>

// GraphSAGE x3 + BN(train stats) + ReLU + head. bf16 features/weights,
// fp32 MFMA accumulation, fp32 BN stats.
// R20: single-kernel partition via block-level atomic reservation:
// LDS hist -> ONE global atomicAdd per (block,bucket) (~245-deep chains,
// gcursor PADDED to 1 bucket/64B line — R8's 247us was same-LINE serial) ->
// LDS-cursor scatter. Kills k_scan, hist round-trip, one launch gap.
// Also: k_final 16 rows/block (4x fewer BN precomputes), NREP 8->16.
// k_layer byte-identical to R19 (best=357.5) except NREP.

#define N_NODES 100000
#define N_EDGES 1250000
#define NB 1563         // buckets == row tiles (64 dst nodes each)
#define BSZ 64
#define CAP 1024        // slots per bucket (mean 800, sigma ~28)
#define BPART 256       // partition blocks
#define NREP 16         // stats replicas (per layer: [NREP][2][128])
#define GSTRIDE 16      // gcursor padding: 1 bucket per 64B line
#define INVN (1.0f / 100000.0f)

typedef short bf16x8 __attribute__((ext_vector_type(8)));
typedef float f32x4 __attribute__((ext_vector_type(4)));
typedef unsigned short u16x8 __attribute__((ext_vector_type(8)));
typedef unsigned short u16x4 __attribute__((ext_vector_type(4)));
typedef unsigned short u16x2 __attribute__((ext_vector_type(2)));

__device__ __forceinline__ float bf2f(unsigned short u) {
  union { unsigned int i; float f; } c; c.i = ((unsigned int)u) << 16; return c.f;
}
__device__ __forceinline__ unsigned short f2bf(float f) {
  union { float f; unsigned int i; } c; c.f = f;
  unsigned int r = (c.i + 0x7FFFu + ((c.i >> 16) & 1u)) >> 16;  // RNE
  return (unsigned short)r;
}
// stats layout per layer: [NREP replicas][2][128] floats
__device__ __forceinline__ void bn_st(const float* stats, const float* gam,
                                      const float* bet, int c, float& s, float& t) {
  float sum = 0.f, sq = 0.f;
  #pragma unroll
  for (int r = 0; r < NREP; r++) {
    sum += stats[r * 256 + c];
    sq  += stats[r * 256 + 128 + c];
  }
  float mu = sum * INVN;
  float var = sq * INVN - mu * mu;
  s = gam[c] * rsqrtf(var + 1e-5f);
  t = bet[c] - mu * s;
}
// async global->LDS, 16B per lane; lds base must be wave-uniform.
__device__ __forceinline__ void gload_lds16(const void* g, void* l) {
  __builtin_amdgcn_global_load_lds(
      (const __attribute__((address_space(1))) unsigned int*)g,
      (__attribute__((address_space(3))) unsigned int*)l, 16, 0, 0);
}

// ----------------- prep: f2bf(x) + weight transpose + init -----------------
__global__ __launch_bounds__(256) void k_prep(
    const float* __restrict__ x, unsigned short* __restrict__ x16,
    const float* __restrict__ W0s, const float* __restrict__ W0n,
    const float* __restrict__ W1s, const float* __restrict__ W1n,
    const float* __restrict__ W2s, const float* __restrict__ W2n,
    unsigned short* __restrict__ wt, float* __restrict__ stats3,
    int* __restrict__ gcursor) {
  int blk = blockIdx.x, t = threadIdx.x;
  if (blk < 6250) {
    int i = blk * 256 + t;
    float4 v = ((const float4*)x)[i];
    u16x4 o;
    o.x = f2bf(v.x); o.y = f2bf(v.y); o.z = f2bf(v.z); o.w = f2bf(v.w);
    ((u16x4*)x16)[i] = o;
  } else if (blk < 6570) {
    int i = (blk - 6250) * 256 + t;
    if (i < 16384) {
      const float* W = (i < 8192) ? W0s : W0n;
      unsigned short* o = wt + (i < 8192 ? 0 : 8192);
      int j = i & 8191;
      int c = j >> 6, k = j & 63;
      o[j] = f2bf(W[k * 128 + c]);
    } else {
      int j = i - 16384;
      int sel = j >> 14;
      j &= 16383;
      const float* W = (sel == 0) ? W1s : (sel == 1) ? W1n : (sel == 2) ? W2s : W2n;
      unsigned short* o = wt + 16384 + sel * 16384;
      int c = j >> 7, k = j & 127;
      o[j] = f2bf(W[k * 128 + c]);
    }
  } else {
    for (int i = t; i < 3 * NREP * 256; i += 256) stats3[i] = 0.f;
    for (int i = t; i < NB * GSTRIDE; i += 256) gcursor[i] = 0;
  }
}

// ----------------- partition: LDS hist -> reserve -> scatter (one kernel) --
// Per block: local histogram of its chunk, one global fetch-add per
// (block,bucket) to reserve a contiguous range (gcursor padded to 64B/line
// so chains are per-address ~245-deep, not same-line), then LDS-cursor
// scatter into the reserved ranges. Intra-bucket order nondeterministic
// (fp32 mean rounding only; counting sort in k_layer is already so).
__global__ __launch_bounds__(512) void k_part(const int* __restrict__ src,
                                              const int* __restrict__ dst,
                                              int* __restrict__ gcursor,
                                              unsigned int* __restrict__ part, int E) {
  __shared__ int hh[NB];
  __shared__ int bbase[NB];
  int t = threadIdx.x;
  int chunk = (E + BPART - 1) / BPART;
  int start = blockIdx.x * chunk;
  int end = min(E, start + chunk);
  for (int b = t; b < NB; b += 512) hh[b] = 0;
  __syncthreads();
  for (int e = start + t; e < end; e += 512) atomicAdd(&hh[dst[e] >> 6], 1);
  __syncthreads();
  for (int b = t; b < NB; b += 512) {
    int c = hh[b];
    bbase[b] = c ? atomicAdd(&gcursor[b * GSTRIDE], c) : 0;
    hh[b] = 0;  // reuse as local cursor
  }
  __syncthreads();
  for (int e = start + t; e < end; e += 512) {
    int d = dst[e];
    int b = d >> 6;
    int pos = bbase[b] + atomicAdd(&hh[b], 1);
    if ((unsigned)pos < (unsigned)CAP)
      part[(size_t)b * CAP + pos] = (unsigned)src[e] | ((unsigned)(d & 63) << 17);
  }
}

// ----------------- fused layer: CSR + gather(+BN) + 64x128 MFMA GEMM ------
// C[bucket rows] = bnrelu?(h[rows])@W1 + mean(bnrelu?(h[src]))@W2 + bias,
// + stats partials. neighT lives in LDS (XOR-swizzled); self A-frags read
// from global (L2-warm after gather). Bs double-buffered (one barrier/step).
template <int DIN, bool BN>
__global__ __launch_bounds__(512, 8) void k_layer(
    const unsigned short* __restrict__ h, const unsigned short* __restrict__ W1t,
    const unsigned short* __restrict__ W2t, const float* __restrict__ bias,
    const unsigned int* __restrict__ part, const int* __restrict__ gcursor,
    unsigned short* __restrict__ C, float* __restrict__ stats, int M,
    const float* __restrict__ statsP, const float* __restrict__ gamP,
    const float* __restrict__ betP) {
  __shared__ unsigned short neighT[64 * DIN];  // 16KB(128)/8KB(64); eraw overlay
  __shared__ unsigned eord[CAP];               // 4KB; redS/redQ overlay
  __shared__ unsigned short Bs[2][128 * 32];   // 16KB W k-chunk (dbuf)
  __shared__ int cnt[BSZ], offv[BSZ], cur[BSZ];
  __shared__ int stealCtr;
  __shared__ float sBN[128], tBN[128];
  unsigned* eraw = (unsigned*)neighT;          // dead before gather writes
  float* redS = (float*)eord;                  // [8][64]; eord dead at epilogue
  float* redQ = redS + 512;

  constexpr int SWZM = (DIN == 128) ? 15 : 7;  // neighT chunk-swizzle mask
  constexpr int KS = DIN / 32;                 // k-steps per half
  int t = threadIdx.x;
  int lane = t & 63, w = t >> 6;
  int l15 = lane & 15, quad = lane >> 4;
  int bkt = blockIdx.x;
  int node0 = bkt * BSZ;
  int nn = min(BSZ, M - node0);

  // ---- init ----
  if (t < BSZ) cnt[t] = 0;
  if (t == 0) stealCtr = 0;
  if (BN && t < 128) bn_st(statsP, gamP, betP, t, sBN[t], tBN[t]);
  __syncthreads();

  // ---- CSR build (bucket-local counting sort) ----
  int ec = gcursor[bkt * GSTRIDE];
  ec = max(0, min(ec, CAP));
  for (int i = t; i < ec; i += 512) {
    unsigned wd = part[(size_t)bkt * CAP + i];
    eraw[i] = wd;
    atomicAdd(&cnt[wd >> 17], 1);
  }
  __syncthreads();
  // wave-0 shfl exclusive scan over the 64 bucket counts (BSZ == wave size)
  if (w == 0) {
    int v = cnt[lane];
    int incl = v;
    #pragma unroll
    for (int o = 1; o < 64; o <<= 1) {
      int u = __shfl_up(incl, o);
      if (lane >= o) incl += u;
    }
    offv[lane] = incl - v;
    cur[lane] = incl - v;
  }
  __syncthreads();
  for (int i = t; i < ec; i += 512) {
    unsigned wd = eraw[i];
    int p = atomicAdd(&cur[wd >> 17], 1);
    eord[p] = wd & 0x1FFFF;
  }
  __syncthreads();  // eraw (neighT space) dead

  // ---- gather + mean (+BN per edge: free under memory bound) ----
  const int G = DIN / 8;
  int li = t & (G - 1);
  float sreg[8], treg[8];
  if (BN) {
    #pragma unroll
    for (int k = 0; k < 8; k++) { sreg[k] = sBN[li * 8 + k]; treg[k] = tBN[li * 8 + k]; }
  }
  for (;;) {
    int nd0 = 0;
    if (li == 0) nd0 = atomicAdd(&stealCtr, 1);
    int nd = __shfl(nd0, 0, G);
    if (nd >= BSZ) break;
    u16x8 o;
    if (nd >= nn) {
      #pragma unroll
      for (int k = 0; k < 8; k++) o[k] = 0;
    } else {
      int s = offv[nd], c = cnt[nd];
      int e = s + c;
      float acc[8] = {0.f, 0.f, 0.f, 0.f, 0.f, 0.f, 0.f, 0.f};
      int j = s;
      for (; j + 2 <= e; j += 2) {
        int sn0 = eord[j], sn1 = eord[j + 1];
        u16x8 v0 = *(const u16x8*)&h[(size_t)sn0 * DIN + li * 8];
        u16x8 v1 = *(const u16x8*)&h[(size_t)sn1 * DIN + li * 8];
        if (BN) {
          #pragma unroll
          for (int k = 0; k < 8; k++)
            acc[k] += fmaxf(fmaf(bf2f(v0[k]), sreg[k], treg[k]), 0.f)
                    + fmaxf(fmaf(bf2f(v1[k]), sreg[k], treg[k]), 0.f);
        } else {
          #pragma unroll
          for (int k = 0; k < 8; k++) acc[k] += bf2f(v0[k]) + bf2f(v1[k]);
        }
      }
      if (j < e) {
        int sn = eord[j];
        u16x8 v = *(const u16x8*)&h[(size_t)sn * DIN + li * 8];
        if (BN) {
          #pragma unroll
          for (int k = 0; k < 8; k++)
            acc[k] += fmaxf(fmaf(bf2f(v[k]), sreg[k], treg[k]), 0.f);
        } else {
          #pragma unroll
          for (int k = 0; k < 8; k++) acc[k] += bf2f(v[k]);
        }
      }
      float inv = 1.0f / fmaxf((float)c, 1.0f);
      #pragma unroll
      for (int k = 0; k < 8; k++) o[k] = f2bf(acc[k] * inv);
    }
    *(u16x8*)&neighT[nd * DIN + ((li * 8) ^ ((nd & SWZM) << 3))] = o;
  }

  // ---- GEMM: 64 rows x 128 cols; Bs dbuf, one barrier per k-step ----
  const int strip = w >> 1;
  const int ch = w & 1;
  const int row = strip * 16 + l15;
  f32x4 acc4[4];
  #pragma unroll
  for (int ct = 0; ct < 4; ct++) acc4[ct] = (f32x4){0.f, 0.f, 0.f, 0.f};

  auto stageBs = [&](int s, int bi) {  // coalesced, linear LDS
    const unsigned short* Wt = (s < KS) ? W1t : W2t;
    int k0 = ((s < KS) ? s : s - KS) * 32;
    int r = t >> 2, prt = t & 3;
    gload_lds16(&Wt[(size_t)r * DIN + k0 + prt * 8], &Bs[bi][(w * 64) * 8]);
  };
  stageBs(0, 0);
  __syncthreads();  // neighT published + Bs(0) drained

  int cb = 0;
  #pragma unroll
  for (int s = 0; s < 2 * KS; s++) {
    if (s + 1 < 2 * KS) stageBs(s + 1, cb ^ 1);
    bf16x8 af;
    if (s < KS) {  // self half: A from global h (L2-warm), optional BN
      int k0 = s * 32;
      u16x8 v = *(const u16x8*)&h[(size_t)(node0 + row) * DIN + k0 + quad * 8];
      if (BN) {
        #pragma unroll
        for (int j = 0; j < 8; j++) {
          int c = k0 + quad * 8 + j;
          v[j] = f2bf(fmaxf(fmaf(bf2f(v[j]), sBN[c], tBN[c]), 0.f));
        }
      }
      af = *(bf16x8*)&v;
    } else {  // neigh half: A from swizzled neighT
      int cc = (s - KS) * 32 + quad * 8;
      u16x8 v = *(const u16x8*)&neighT[row * DIN + (cc ^ ((row & SWZM) << 3))];
      af = *(bf16x8*)&v;
    }
    #pragma unroll
    for (int ct = 0; ct < 4; ct++) {
      bf16x8 bfr = *(const bf16x8*)&Bs[cb][(ch * 64 + ct * 16 + l15) * 32 + quad * 8];
      acc4[ct] = __builtin_amdgcn_mfma_f32_16x16x32_bf16(af, bfr, acc4[ct], 0, 0, 0);
    }
    if (s + 1 < 2 * KS) __syncthreads();  // Bs(s+1) landed; Bs(cb) consumed
    cb ^= 1;
  }

  // ---- epilogue: bias, C write, stats partials ----
  float bcol[4], ls[4], lq[4];
  #pragma unroll
  for (int ct = 0; ct < 4; ct++) {
    bcol[ct] = bias[ch * 64 + ct * 16 + l15];
    ls[ct] = 0.f; lq[ct] = 0.f;
  }
  #pragma unroll
  for (int r = 0; r < 4; r++) {
    int orow = node0 + strip * 16 + quad * 4 + r;
    if (orow < M) {
      #pragma unroll
      for (int ct = 0; ct < 4; ct++) {
        float v = acc4[ct][r] + bcol[ct];
        C[(size_t)orow * 128 + ch * 64 + ct * 16 + l15] = f2bf(v);
        ls[ct] += v; lq[ct] += v * v;
      }
    }
  }
  #pragma unroll
  for (int ct = 0; ct < 4; ct++) {  // reduce over quads (rows of strip)
    ls[ct] += __shfl_xor(ls[ct], 16); ls[ct] += __shfl_xor(ls[ct], 32);
    lq[ct] += __shfl_xor(lq[ct], 16); lq[ct] += __shfl_xor(lq[ct], 32);
  }
  if (quad == 0) {
    #pragma unroll
    for (int ct = 0; ct < 4; ct++) {
      redS[w * 64 + ct * 16 + l15] = ls[ct];
      redQ[w * 64 + ct * 16 + l15] = lq[ct];
    }
  }
  __syncthreads();
  if (t < 128) {
    int ch2 = t >> 6, c6 = t & 63;
    float s = 0.f, q = 0.f;
    #pragma unroll
    for (int st = 0; st < 4; st++) {
      s += redS[(st * 2 + ch2) * 64 + c6];
      q += redQ[(st * 2 + ch2) * 64 + c6];
    }
    int rep = (bkt & (NREP - 1)) * 256;  // NREP replicas (~98-deep chains)
    atomicAdd(&stats[rep + t], s);
    atomicAdd(&stats[rep + 128 + t], q);
  }
}

// ----------------- fused BN + ReLU + classifier -----------------
// 16 rows/block: BN-coeff LDS precompute amortized 4x vs R19.
__global__ __launch_bounds__(256) void k_final(
    const unsigned short* __restrict__ h,
    const float* __restrict__ statsP, const float* __restrict__ gamP,
    const float* __restrict__ betP, const float* __restrict__ Wc,
    const float* __restrict__ bc, float* __restrict__ out, int n) {
  __shared__ float sS[128], sT[128];
  int t = threadIdx.x;
  if (t < 128) bn_st(statsP, gamP, betP, t, sS[t], sT[t]);
  __syncthreads();
  int lane = t & 63;
  int wv = t >> 6;
  int c0 = lane * 2;
  float s0 = sS[c0], t0 = sT[c0], s1 = sS[c0 + 1], t1 = sT[c0 + 1];
  float4 w4 = ((const float4*)Wc)[lane];  // {Wc[c0][0],Wc[c0][1],Wc[c0+1][0],Wc[c0+1][1]}
  #pragma unroll
  for (int r = 0; r < 4; r++) {
    int row = blockIdx.x * 16 + wv * 4 + r;
    if (row >= n) break;
    u16x2 hv = *(const u16x2*)&h[(size_t)row * 128 + c0];
    float v0 = fmaxf(fmaf(bf2f(hv.x), s0, t0), 0.f);
    float v1 = fmaxf(fmaf(bf2f(hv.y), s1, t1), 0.f);
    float acc0 = v0 * w4.x + v1 * w4.z;
    float acc1 = v0 * w4.y + v1 * w4.w;
    #pragma unroll
    for (int off = 32; off > 0; off >>= 1) {
      acc0 += __shfl_down(acc0, off);
      acc1 += __shfl_down(acc1, off);
    }
    if (lane == 0) {
      out[row * 2 + 0] = acc0 + bc[0];
      out[row * 2 + 1] = acc1 + bc[1];
    }
  }
}

extern "C" void kernel_launch(void* const* d_in, const int* in_sizes, int n_in,
                              void* d_out, int out_size, void* d_ws, size_t ws_size,
                              hipStream_t stream) {
  const float* x   = (const float*)d_in[0];
  const int* src   = (const int*)d_in[1];
  const int* dst   = (const int*)d_in[2];
  const float* Wself[3] = {(const float*)d_in[3], (const float*)d_in[8],  (const float*)d_in[13]};
  const float* bself[3] = {(const float*)d_in[4], (const float*)d_in[9],  (const float*)d_in[14]};
  const float* Wngh[3]  = {(const float*)d_in[5], (const float*)d_in[10], (const float*)d_in[15]};
  const float* gam[3]   = {(const float*)d_in[6], (const float*)d_in[11], (const float*)d_in[16]};
  const float* bet[3]   = {(const float*)d_in[7], (const float*)d_in[12], (const float*)d_in[17]};
  const float* Wc = (const float*)d_in[18];
  const float* bc = (const float*)d_in[19];
  float* out = (float*)d_out;

  const int N = N_NODES, E = N_EDGES;

  unsigned short* x16 = (unsigned short*)d_ws;        // N*64
  unsigned short* b0  = x16 + (size_t)N * 64;         // N*128 (slack)
  unsigned short* b1  = b0 + (size_t)N * 128;
  unsigned short* b2  = b1 + (size_t)N * 128;
  unsigned short* wt  = b2 + (size_t)N * 128;         // 81920
  unsigned int* part  = (unsigned int*)(wt + 81920);  // NB*CAP
  int* gcursor  = (int*)(part + (size_t)NB * CAP);    // NB*GSTRIDE (padded)
  float* stats3 = (float*)(gcursor + NB * GSTRIDE);   // 3*NREP*256

  // ---- prep: x->bf16, weights, zero stats + gcursor ----
  k_prep<<<6571, 256, 0, stream>>>(
      x, x16, Wself[0], Wngh[0], Wself[1], Wngh[1], Wself[2], Wngh[2],
      wt, stats3, gcursor);

  // ---- partition: hist -> reserve -> scatter (one kernel) ----
  k_part<<<BPART, 512, 0, stream>>>(src, dst, gcursor, part, E);

  // ---- fused layers ----
  k_layer<64, false><<<NB, 512, 0, stream>>>(
      x16, wt + 0, wt + 8192, bself[0], part, gcursor, b1, stats3 + 0, N,
      nullptr, nullptr, nullptr);
  k_layer<128, true><<<NB, 512, 0, stream>>>(
      b1, wt + 16384, wt + 32768, bself[1], part, gcursor, b2, stats3 + 4096, N,
      stats3 + 0, gam[0], bet[0]);
  k_layer<128, true><<<NB, 512, 0, stream>>>(
      b2, wt + 49152, wt + 65536, bself[2], part, gcursor, b1, stats3 + 8192, N,
      stats3 + 4096, gam[1], bet[1]);

  // ---- fused BN2 + ReLU + classifier ----
  k_final<<<(N + 15) / 16, 256, 0, stream>>>(b1, stats3 + 8192, gam[2], bet[2],
                                             Wc, bc, out, N);
}